// Round 1
// baseline (521.893 us; speedup 1.0000x reference)
//
#include <hip/hip_runtime.h>
#include <stdint.h>

namespace {

constexpr int kB = 16;
constexpr int kC = 80;
constexpr int kNLev = 5;
constexpr int kTopK = 1000;
constexpr int kDets = 100;
constexpr int kNBins = 2048;
constexpr int kCap = 4096;
constexpr float kScoreT = 0.2f;
constexpr float kNmsT = 0.6f;
constexpr int kChunk = 16384;
constexpr int kHW[5] = {16384, 4096, 1024, 256, 64};
constexpr int kLvlOff[5] = {0, 16384, 20480, 21504, 21760};
constexpr int kHWTot = 21824;
constexpr int kNTot = kNLev * kTopK;  // 5000

struct LvlPtrs {
  const float* reg[5];
  const float* anc[5];
};

__device__ __forceinline__ float sigm(float x) {
  return 1.0f / (1.0f + expf(-x));
}

// ---- precompute sigmoid(ctr) per location ----
__global__ void ksigctr(const float* __restrict__ c0, const float* __restrict__ c1,
                        const float* __restrict__ c2, const float* __restrict__ c3,
                        const float* __restrict__ c4, float* __restrict__ sct) {
  int gid = blockIdx.x * blockDim.x + threadIdx.x;
  if (gid >= kB * kHWTot) return;
  int b = gid / kHWTot;
  int pa = gid - b * kHWTot;
  const float* src; int hw; int off;
  if (pa < 16384)      { src = c0; off = 0;     hw = 16384; }
  else if (pa < 20480) { src = c1; off = 16384; hw = 4096; }
  else if (pa < 21504) { src = c2; off = 20480; hw = 1024; }
  else if (pa < 21760) { src = c3; off = 21504; hw = 256; }
  else                 { src = c4; off = 21760; hw = 64; }
  sct[gid] = sigm(src[(size_t)b * hw + (pa - off)]);
}

// ---- pass 1: histogram of scores per (b, level) ----
template<int L>
__global__ void khist(const float* __restrict__ cls, const float* __restrict__ sct,
                      unsigned int* __restrict__ ghist) {
  constexpr int HW = kHW[L];
  constexpr int N = HW * kC;
  constexpr int CPB = (N + kChunk - 1) / kChunk;
  const int b = blockIdx.x / CPB;
  const int ch = blockIdx.x % CPB;
  const int start = ch * kChunk;
  const int end = (start + kChunk < N) ? (start + kChunk) : N;
  __shared__ unsigned int lh[kNBins];
  for (int i = threadIdx.x; i < kNBins; i += blockDim.x) lh[i] = 0;
  __syncthreads();
  const float* clsb = cls + (size_t)b * N;
  const float* sctb = sct + (size_t)b * kHWTot + kLvlOff[L];
  for (int e = start + threadIdx.x; e < end; e += blockDim.x) {
    float st = sctb[e / kC];
    float sc = sqrtf(sigm(clsb[e]) * st);
    if (sc > kScoreT) {
      int bin = (int)((sc - kScoreT) * 2560.0f);
      if (bin > kNBins - 1) bin = kNBins - 1;
      atomicAdd(&lh[bin], 1u);
    }
  }
  __syncthreads();
  unsigned int* gh = ghist + (size_t)(b * kNLev + L) * kNBins;
  for (int i = threadIdx.x; i < kNBins; i += blockDim.x)
    if (lh[i]) atomicAdd(&gh[i], lh[i]);
}

// ---- find cutoff bin: smallest bin with suffix-count >= TOPK ----
__global__ void kcutoff(const unsigned int* __restrict__ ghist, int* __restrict__ cutoff) {
  const int g = blockIdx.x;
  const unsigned int* h = ghist + (size_t)g * kNBins;
  __shared__ unsigned int lh[kNBins];
  __shared__ unsigned int tsum[256];
  for (int i = threadIdx.x; i < kNBins; i += 256) lh[i] = h[i];
  __syncthreads();
  unsigned int s = 0;
  for (int k = 0; k < kNBins / 256; ++k) s += lh[threadIdx.x * (kNBins / 256) + k];
  tsum[threadIdx.x] = s;
  __syncthreads();
  if (threadIdx.x == 0) {
    unsigned int acc = 0;
    for (int t = 255; t >= 0; --t) {
      if (acc + tsum[t] >= (unsigned)kTopK) {
        int c = 0;
        for (int bin = t * 8 + 7; bin >= t * 8; --bin) {
          acc += lh[bin];
          if (acc >= (unsigned)kTopK) { c = bin; break; }
        }
        cutoff[g] = c;
        return;
      }
      acc += tsum[t];
    }
    cutoff[g] = 0;
  }
}

// ---- pass 2: compact candidates in bins >= cutoff ----
template<int L>
__global__ void kcompact(const float* __restrict__ cls, const float* __restrict__ sct,
                         const int* __restrict__ cutoff, unsigned int* __restrict__ cnt,
                         unsigned long long* __restrict__ cand) {
  constexpr int HW = kHW[L];
  constexpr int N = HW * kC;
  constexpr int CPB = (N + kChunk - 1) / kChunk;
  const int b = blockIdx.x / CPB;
  const int ch = blockIdx.x % CPB;
  const int start = ch * kChunk;
  const int end = (start + kChunk < N) ? (start + kChunk) : N;
  const int g = b * kNLev + L;
  const int cut = cutoff[g];
  const float* clsb = cls + (size_t)b * N;
  const float* sctb = sct + (size_t)b * kHWTot + kLvlOff[L];
  for (int e = start + threadIdx.x; e < end; e += blockDim.x) {
    float st = sctb[e / kC];
    float sc = sqrtf(sigm(clsb[e]) * st);
    if (sc > kScoreT) {
      int bin = (int)((sc - kScoreT) * 2560.0f);
      if (bin > kNBins - 1) bin = kNBins - 1;
      if (bin >= cut) {
        unsigned int slot = atomicAdd(&cnt[g], 1u);
        if (slot < (unsigned)kCap) {
          unsigned int inv = 0xFFFFFFu - (((unsigned)L << 21) | (unsigned)e);
          cand[(size_t)g * kCap + slot] =
              ((unsigned long long)__float_as_uint(sc) << 24) | inv;
        }
      }
    }
  }
}

// ---- per-(b,level) bitonic sort desc, truncate to top-1000, pad ----
__global__ void ksortlevel(const unsigned long long* __restrict__ cand,
                           const unsigned int* __restrict__ cnt,
                           unsigned long long* __restrict__ lvlsorted) {
  const int g = blockIdx.x;
  const int l = g % kNLev;
  __shared__ unsigned long long s[kCap];
  unsigned int n = cnt[g];
  if (n > (unsigned)kCap) n = kCap;
  for (int i = threadIdx.x; i < kCap; i += 256)
    s[i] = (i < (int)n) ? cand[(size_t)g * kCap + i] : 0ull;
  __syncthreads();
  for (int k = 2; k <= kCap; k <<= 1) {
    for (int j = k >> 1; j > 0; j >>= 1) {
      for (int i = threadIdx.x; i < kCap; i += 256) {
        int ixj = i ^ j;
        if (ixj > i) {
          unsigned long long a = s[i], bb = s[ixj];
          bool sw = ((i & k) == 0) ? (a < bb) : (a > bb);  // descending
          if (sw) { s[i] = bb; s[ixj] = a; }
        }
      }
      __syncthreads();
    }
  }
  for (int p = threadIdx.x; p < kTopK; p += 256) {
    // pad keys: unique, tiny (score bits 0 => score 0), descending in p
    unsigned long long key = (p < (int)n)
        ? s[p]
        : (unsigned long long)(kNTot - (l * kTopK + p));
    lvlsorted[(size_t)g * kTopK + p] = key;
  }
}

__device__ __forceinline__ void decode_key(unsigned long long key, int b, const LvlPtrs& P,
                                           float4* box, int* label_out, float* score_out) {
  float sc = __uint_as_float((unsigned int)(key >> 24));
  *score_out = sc;
  if (!(sc > kScoreT)) { *box = make_float4(0.f, 0.f, 0.f, 0.f); *label_out = -1; return; }
  unsigned int pk = 0xFFFFFFu - (unsigned int)(key & 0xFFFFFFu);
  int l = pk >> 21;
  int idx = pk & 0x1FFFFF;
  int pos = idx / kC;
  int label = idx - pos * kC;
  int hw = 16384 >> (2 * l);
  const float* rg = P.reg[l] + ((size_t)b * hw + pos) * 4;
  const float* an = P.anc[l] + (size_t)pos * 4;
  float a0 = an[0], a1 = an[1], a2 = an[2], a3 = an[3];
  float cx = (a0 + a2) * 0.5f, cy = (a1 + a3) * 0.5f;
  float w = a2 - a0, h = a3 - a1;
  float x0 = cx - rg[0] * w, y0 = cy - rg[1] * h;
  float x1 = cx + rg[2] * w, y1 = cy + rg[3] * h;
  x0 = fminf(fmaxf(x0, 0.f), 1024.f);
  y0 = fminf(fmaxf(y0, 0.f), 1024.f);
  x1 = fminf(fmaxf(x1, 0.f), 1024.f);
  y1 = fminf(fmaxf(y1, 0.f), 1024.f);
  *box = make_float4(x0, y0, x1, y1);
  *label_out = label;
}

// ---- merge 5 sorted lists into global desc order via rank; decode offset boxes ----
__global__ void krank(const unsigned long long* __restrict__ lvlsorted,
                      unsigned long long* __restrict__ skey,
                      float4* __restrict__ obox, LvlPtrs P) {
  int gid = blockIdx.x * blockDim.x + threadIdx.x;
  if (gid >= kB * kNTot) return;
  int b = gid / kNTot;
  int r0 = gid - b * kNTot;
  int a = r0 / kTopK, p = r0 - a * kTopK;
  const unsigned long long* base = lvlsorted + (size_t)b * kNTot;
  unsigned long long key = base[a * kTopK + p];
  int rank = p;
  for (int a2 = 0; a2 < kNLev; ++a2) {
    if (a2 == a) continue;
    const unsigned long long* lst = base + a2 * kTopK;
    int lo = 0, hi = kTopK;
    while (lo < hi) {
      int mid = (lo + hi) >> 1;
      if (lst[mid] > key) lo = mid + 1; else hi = mid;
    }
    rank += lo;
  }
  float4 box; int label; float sc;
  decode_key(key, b, P, &box, &label, &sc);
  float off = (sc > kScoreT) ? (float)label * 1025.0f : 0.0f;
  skey[(size_t)b * kNTot + rank] = key;
  obox[(size_t)b * kNTot + rank] =
      make_float4(box.x + off, box.y + off, box.z + off, box.w + off);
}

// ---- greedy NMS scan: one wave per image ----
__global__ void __launch_bounds__(64)
knms(const unsigned long long* __restrict__ skey, const float4* __restrict__ obox,
     LvlPtrs P, float* __restrict__ out) {
  const int b = blockIdx.x;
  const int lane = threadIdx.x;
  __shared__ float4 kbox[kDets];
  __shared__ float karea[kDets];
  __shared__ unsigned long long kkey[kDets];
  const unsigned long long* keys = skey + (size_t)b * kNTot;
  const float4* boxes = obox + (size_t)b * kNTot;
  int nkept = 0;
  for (int base = 0; base < kNTot && nkept < kDets; base += 64) {
    int j = base + lane;
    unsigned long long key = (j < kNTot) ? keys[j] : 0ull;
    float sc = __uint_as_float((unsigned int)(key >> 24));
    bool scval = (j < kNTot) && (sc > kScoreT);
    if (__ballot(scval) == 0ull) break;  // sorted desc: nothing valid remains
    float4 bx = make_float4(0.f, 0.f, 0.f, 0.f);
    if (scval) bx = boxes[j];
    float area = (bx.z - bx.x) * (bx.w - bx.y);
    bool alive = scval;
    for (int k = 0; k < nkept; ++k) {
      float4 kb = kbox[k];
      float xx1 = fmaxf(kb.x, bx.x), yy1 = fmaxf(kb.y, bx.y);
      float xx2 = fminf(kb.z, bx.z), yy2 = fminf(kb.w, bx.w);
      float inter = fmaxf(xx2 - xx1, 0.f) * fmaxf(yy2 - yy1, 0.f);
      float iou = inter / (area + karea[k] - inter + 1e-9f);
      if (iou > kNmsT) alive = false;
    }
    unsigned long long mask = __ballot(alive);
    while (mask != 0ull && nkept < kDets) {
      int lead = (int)__builtin_ctzll(mask);
      float lx = __shfl(bx.x, lead);
      float ly = __shfl(bx.y, lead);
      float lz = __shfl(bx.z, lead);
      float lw = __shfl(bx.w, lead);
      float la = __shfl(area, lead);
      unsigned int khi = (unsigned int)__shfl((int)(key >> 32), lead);
      unsigned int klo = (unsigned int)__shfl((int)(key & 0xFFFFFFFFull), lead);
      if (lane == 0) {
        kbox[nkept] = make_float4(lx, ly, lz, lw);
        karea[nkept] = la;
        kkey[nkept] = (((unsigned long long)khi) << 32) | (unsigned long long)klo;
      }
      __syncthreads();
      ++nkept;
      // suppress within chunk vs lead (lead suppresses itself: IoU == 1)
      float xx1 = fmaxf(lx, bx.x), yy1 = fmaxf(ly, bx.y);
      float xx2 = fminf(lz, bx.z), yy2 = fminf(lw, bx.w);
      float inter = fmaxf(xx2 - xx1, 0.f) * fmaxf(yy2 - yy1, 0.f);
      float iou = inter / (area + la - inter + 1e-9f);
      if (iou > kNmsT) alive = false;
      mask = __ballot(alive);
    }
  }
  // outputs: boxes [B,100,4] | scores [B,100] | labels [B,100]
  for (int s = lane; s < kDets; s += 64) {
    float4 bo = make_float4(0.f, 0.f, 0.f, 0.f);
    float so = 0.f, lo = -1.f;
    if (s < nkept) {
      float4 box; int label; float sc;
      decode_key(kkey[s], b, P, &box, &label, &sc);
      bo = box; so = sc; lo = (float)label;
    }
    size_t bi = (size_t)b * kDets + s;
    out[bi * 4 + 0] = bo.x;
    out[bi * 4 + 1] = bo.y;
    out[bi * 4 + 2] = bo.z;
    out[bi * 4 + 3] = bo.w;
    out[(size_t)kB * kDets * 4 + bi] = so;
    out[(size_t)kB * kDets * 5 + bi] = lo;
  }
}

}  // namespace

extern "C" void kernel_launch(void* const* d_in, const int* in_sizes, int n_in,
                              void* d_out, int out_size, void* d_ws, size_t ws_size,
                              hipStream_t stream) {
  const float* cls[5]; const float* ctr[5];
  LvlPtrs P;
  for (int l = 0; l < 5; ++l) {
    cls[l]   = (const float*)d_in[4 * l + 0];
    ctr[l]   = (const float*)d_in[4 * l + 1];
    P.reg[l] = (const float*)d_in[4 * l + 2];
    P.anc[l] = (const float*)d_in[4 * l + 3];
  }

  char* w = (char*)d_ws;
  unsigned int* hist = (unsigned int*)w;          w += (size_t)80 * kNBins * 4;  // 655360
  int* cutoff = (int*)w;                          w += 80 * 4;
  unsigned int* cnt = (unsigned int*)w;           w += 80 * 4;
  unsigned long long* cand = (unsigned long long*)w;      w += (size_t)80 * kCap * 8;
  unsigned long long* lvlsorted = (unsigned long long*)w; w += (size_t)80 * kTopK * 8;
  unsigned long long* skeyp = (unsigned long long*)w;     w += (size_t)kB * kNTot * 8;
  float4* oboxp = (float4*)w;                     w += (size_t)kB * kNTot * 16;
  float* sct = (float*)w;                         w += (size_t)kB * kHWTot * 4;

  // zero hist + cutoff + cnt (contiguous)
  hipMemsetAsync(hist, 0, (size_t)80 * kNBins * 4 + 80 * 8, stream);

  int sblocks = (kB * kHWTot + 255) / 256;
  ksigctr<<<sblocks, 256, 0, stream>>>(ctr[0], ctr[1], ctr[2], ctr[3], ctr[4], sct);

  auto cpb = [](int hw) { return (hw * kC + kChunk - 1) / kChunk; };
  khist<0><<<kB * cpb(kHW[0]), 256, 0, stream>>>(cls[0], sct, hist);
  khist<1><<<kB * cpb(kHW[1]), 256, 0, stream>>>(cls[1], sct, hist);
  khist<2><<<kB * cpb(kHW[2]), 256, 0, stream>>>(cls[2], sct, hist);
  khist<3><<<kB * cpb(kHW[3]), 256, 0, stream>>>(cls[3], sct, hist);
  khist<4><<<kB * cpb(kHW[4]), 256, 0, stream>>>(cls[4], sct, hist);

  kcutoff<<<80, 256, 0, stream>>>(hist, cutoff);

  kcompact<0><<<kB * cpb(kHW[0]), 256, 0, stream>>>(cls[0], sct, cutoff, cnt, cand);
  kcompact<1><<<kB * cpb(kHW[1]), 256, 0, stream>>>(cls[1], sct, cutoff, cnt, cand);
  kcompact<2><<<kB * cpb(kHW[2]), 256, 0, stream>>>(cls[2], sct, cutoff, cnt, cand);
  kcompact<3><<<kB * cpb(kHW[3]), 256, 0, stream>>>(cls[3], sct, cutoff, cnt, cand);
  kcompact<4><<<kB * cpb(kHW[4]), 256, 0, stream>>>(cls[4], sct, cutoff, cnt, cand);

  ksortlevel<<<80, 256, 0, stream>>>(cand, cnt, lvlsorted);

  int rblocks = (kB * kNTot + 255) / 256;
  krank<<<rblocks, 256, 0, stream>>>(lvlsorted, skeyp, oboxp, P);

  knms<<<kB, 64, 0, stream>>>(skeyp, oboxp, P, (float*)d_out);
}

// Round 2
// 240.197 us; speedup vs baseline: 2.1728x; 2.1728x over previous
//
#include <hip/hip_runtime.h>
#include <stdint.h>

namespace {

constexpr int kB = 16;
constexpr int kC = 80;
constexpr int kNLev = 5;
constexpr int kTopK = 1000;
constexpr int kDets = 100;
constexpr int kNBins = 2048;
constexpr int kCap = 4096;
constexpr float kScoreT = 0.2f;
constexpr float kNmsT = 0.6f;
constexpr int kChunk = 16384;
constexpr int kHW[5] = {16384, 4096, 1024, 256, 64};
constexpr int kLvlOff[5] = {0, 16384, 20480, 21504, 21760};
constexpr int kHWTot = 21824;
constexpr int kNTot = kNLev * kTopK;  // 5000
// chunks per image: L0: 80, L1: 20, L2: 5, L3: 2, L4: 1  => 108
constexpr int kChunksPerImg = 108;

struct LvlPtrs {
  const float* reg[5];
  const float* anc[5];
};

struct ClsPtrs {
  const float* cls[5];
};

__device__ __forceinline__ float sigm(float x) {
  return 1.0f / (1.0f + expf(-x));
}

__device__ __forceinline__ void chunk_map(int c, int* L, int* ch) {
  if (c < 80)       { *L = 0; *ch = c; }
  else if (c < 100) { *L = 1; *ch = c - 80; }
  else if (c < 105) { *L = 2; *ch = c - 100; }
  else if (c < 107) { *L = 3; *ch = c - 105; }
  else              { *L = 4; *ch = 0; }
}

// ---- precompute sigmoid(ctr) per location ----
__global__ void ksigctr(const float* __restrict__ c0, const float* __restrict__ c1,
                        const float* __restrict__ c2, const float* __restrict__ c3,
                        const float* __restrict__ c4, float* __restrict__ sct) {
  int gid = blockIdx.x * blockDim.x + threadIdx.x;
  if (gid >= kB * kHWTot) return;
  int b = gid / kHWTot;
  int pa = gid - b * kHWTot;
  const float* src; int hw; int off;
  if (pa < 16384)      { src = c0; off = 0;     hw = 16384; }
  else if (pa < 20480) { src = c1; off = 16384; hw = 4096; }
  else if (pa < 21504) { src = c2; off = 20480; hw = 1024; }
  else if (pa < 21760) { src = c3; off = 21504; hw = 256; }
  else                 { src = c4; off = 21760; hw = 64; }
  sct[gid] = sigm(src[(size_t)b * hw + (pa - off)]);
}

// ---- pass 1: histogram of scores per (b, level), all levels fused ----
__global__ void khist_all(ClsPtrs CP, const float* __restrict__ sct,
                          unsigned int* __restrict__ ghist) {
  const int b = blockIdx.x / kChunksPerImg;
  const int c = blockIdx.x % kChunksPerImg;
  int L, ch; chunk_map(c, &L, &ch);
  const int HW = 16384 >> (2 * L);
  const int N = HW * kC;
  const int start = ch * kChunk;
  const int end = (start + kChunk < N) ? (start + kChunk) : N;
  __shared__ unsigned int lh[kNBins];
  for (int i = threadIdx.x; i < kNBins; i += blockDim.x) lh[i] = 0;
  __syncthreads();
  const float* clsb = CP.cls[L] + (size_t)b * N;
  const float* sctb = sct + (size_t)b * kHWTot + kLvlOff[L];
  for (int e0 = start + threadIdx.x * 4; e0 < end; e0 += blockDim.x * 4) {
    float4 v = *reinterpret_cast<const float4*>(clsb + e0);
    float cv[4] = {v.x, v.y, v.z, v.w};
#pragma unroll
    for (int q = 0; q < 4; ++q) {
      int e = e0 + q;
      float st = sctb[e / kC];
      float sc = sqrtf(sigm(cv[q]) * st);
      if (sc > kScoreT) {
        int bin = (int)((sc - kScoreT) * 2560.0f);
        if (bin > kNBins - 1) bin = kNBins - 1;
        atomicAdd(&lh[bin], 1u);
      }
    }
  }
  __syncthreads();
  unsigned int* gh = ghist + (size_t)(b * kNLev + L) * kNBins;
  for (int i = threadIdx.x; i < kNBins; i += blockDim.x)
    if (lh[i]) atomicAdd(&gh[i], lh[i]);
}

// ---- find cutoff bin: smallest bin with suffix-count >= TOPK ----
__global__ void kcutoff(const unsigned int* __restrict__ ghist, int* __restrict__ cutoff) {
  const int g = blockIdx.x;
  const unsigned int* h = ghist + (size_t)g * kNBins;
  __shared__ unsigned int lh[kNBins];
  __shared__ unsigned int tsum[256];
  for (int i = threadIdx.x; i < kNBins; i += 256) lh[i] = h[i];
  __syncthreads();
  unsigned int s = 0;
  for (int k = 0; k < kNBins / 256; ++k) s += lh[threadIdx.x * (kNBins / 256) + k];
  tsum[threadIdx.x] = s;
  __syncthreads();
  if (threadIdx.x == 0) {
    unsigned int acc = 0;
    for (int t = 255; t >= 0; --t) {
      if (acc + tsum[t] >= (unsigned)kTopK) {
        int c = 0;
        for (int bin = t * 8 + 7; bin >= t * 8; --bin) {
          acc += lh[bin];
          if (acc >= (unsigned)kTopK) { c = bin; break; }
        }
        cutoff[g] = c;
        return;
      }
      acc += tsum[t];
    }
    cutoff[g] = 0;
  }
}

// ---- pass 2: compact candidates in bins >= cutoff, all levels fused ----
__global__ void kcompact_all(ClsPtrs CP, const float* __restrict__ sct,
                             const int* __restrict__ cutoff, unsigned int* __restrict__ cnt,
                             unsigned long long* __restrict__ cand) {
  const int b = blockIdx.x / kChunksPerImg;
  const int c = blockIdx.x % kChunksPerImg;
  int L, ch; chunk_map(c, &L, &ch);
  const int HW = 16384 >> (2 * L);
  const int N = HW * kC;
  const int start = ch * kChunk;
  const int end = (start + kChunk < N) ? (start + kChunk) : N;
  const int g = b * kNLev + L;
  const int cut = cutoff[g];
  const float* clsb = CP.cls[L] + (size_t)b * N;
  const float* sctb = sct + (size_t)b * kHWTot + kLvlOff[L];
  for (int e0 = start + threadIdx.x * 4; e0 < end; e0 += blockDim.x * 4) {
    float4 v = *reinterpret_cast<const float4*>(clsb + e0);
    float cv[4] = {v.x, v.y, v.z, v.w};
#pragma unroll
    for (int q = 0; q < 4; ++q) {
      int e = e0 + q;
      float st = sctb[e / kC];
      float sc = sqrtf(sigm(cv[q]) * st);
      if (sc > kScoreT) {
        int bin = (int)((sc - kScoreT) * 2560.0f);
        if (bin > kNBins - 1) bin = kNBins - 1;
        if (bin >= cut) {
          unsigned int slot = atomicAdd(&cnt[g], 1u);
          if (slot < (unsigned)kCap) {
            unsigned int inv = 0xFFFFFFu - (((unsigned)L << 21) | (unsigned)e);
            cand[(size_t)g * kCap + slot] =
                ((unsigned long long)__float_as_uint(sc) << 24) | inv;
          }
        }
      }
    }
  }
}

// ---- per-(b,level) rank-scatter: sorted top-1000 without a sort ----
__global__ void __launch_bounds__(1024)
krankl(const unsigned long long* __restrict__ cand, const unsigned int* __restrict__ cnt,
       unsigned long long* __restrict__ lvlsorted) {
  const int g = blockIdx.x;
  const int l = g % kNLev;
  __shared__ unsigned long long s[kCap];
  unsigned int nu = cnt[g];
  const int n = (nu > (unsigned)kCap) ? kCap : (int)nu;
  for (int i = threadIdx.x; i < n; i += 1024)
    s[i] = cand[(size_t)g * kCap + i];
  __syncthreads();
  // pad slots [n, kTopK): unique, tiny (score decodes to 0), descending in p
  for (int p = n + (int)threadIdx.x; p < kTopK; p += 1024)
    lvlsorted[(size_t)g * kTopK + p] =
        (unsigned long long)(kNTot - (l * kTopK + p));
  // rank-scatter: keys unique -> ranks are a permutation of [0, n)
  for (int i = threadIdx.x; i < n; i += 1024) {
    const unsigned long long ki = s[i];
    int r = 0;
#pragma unroll 8
    for (int j = 0; j < n; ++j) r += (s[j] > ki) ? 1 : 0;
    if (r < kTopK) lvlsorted[(size_t)g * kTopK + r] = ki;
  }
}

__device__ __forceinline__ void decode_key(unsigned long long key, int b, const LvlPtrs& P,
                                           float4* box, int* label_out, float* score_out) {
  float sc = __uint_as_float((unsigned int)(key >> 24));
  *score_out = sc;
  if (!(sc > kScoreT)) { *box = make_float4(0.f, 0.f, 0.f, 0.f); *label_out = -1; return; }
  unsigned int pk = 0xFFFFFFu - (unsigned int)(key & 0xFFFFFFu);
  int l = pk >> 21;
  int idx = pk & 0x1FFFFF;
  int pos = idx / kC;
  int label = idx - pos * kC;
  int hw = 16384 >> (2 * l);
  const float* rg = P.reg[l] + ((size_t)b * hw + pos) * 4;
  const float* an = P.anc[l] + (size_t)pos * 4;
  float a0 = an[0], a1 = an[1], a2 = an[2], a3 = an[3];
  float cx = (a0 + a2) * 0.5f, cy = (a1 + a3) * 0.5f;
  float w = a2 - a0, h = a3 - a1;
  float x0 = cx - rg[0] * w, y0 = cy - rg[1] * h;
  float x1 = cx + rg[2] * w, y1 = cy + rg[3] * h;
  x0 = fminf(fmaxf(x0, 0.f), 1024.f);
  y0 = fminf(fmaxf(y0, 0.f), 1024.f);
  x1 = fminf(fmaxf(x1, 0.f), 1024.f);
  y1 = fminf(fmaxf(y1, 0.f), 1024.f);
  *box = make_float4(x0, y0, x1, y1);
  *label_out = label;
}

// ---- merge 5 sorted lists into global desc order via rank; decode offset boxes ----
__global__ void krank(const unsigned long long* __restrict__ lvlsorted,
                      unsigned long long* __restrict__ skey,
                      float4* __restrict__ obox, LvlPtrs P) {
  int gid = blockIdx.x * blockDim.x + threadIdx.x;
  if (gid >= kB * kNTot) return;
  int b = gid / kNTot;
  int r0 = gid - b * kNTot;
  int a = r0 / kTopK, p = r0 - a * kTopK;
  const unsigned long long* base = lvlsorted + (size_t)b * kNTot;
  unsigned long long key = base[a * kTopK + p];
  int rank = p;
  for (int a2 = 0; a2 < kNLev; ++a2) {
    if (a2 == a) continue;
    const unsigned long long* lst = base + a2 * kTopK;
    int lo = 0, hi = kTopK;
    while (lo < hi) {
      int mid = (lo + hi) >> 1;
      if (lst[mid] > key) lo = mid + 1; else hi = mid;
    }
    rank += lo;
  }
  float4 box; int label; float sc;
  decode_key(key, b, P, &box, &label, &sc);
  float off = (sc > kScoreT) ? (float)label * 1025.0f : 0.0f;
  skey[(size_t)b * kNTot + rank] = key;
  obox[(size_t)b * kNTot + rank] =
      make_float4(box.x + off, box.y + off, box.z + off, box.w + off);
}

// ---- greedy NMS scan: one wave per image ----
__global__ void __launch_bounds__(64)
knms(const unsigned long long* __restrict__ skey, const float4* __restrict__ obox,
     LvlPtrs P, float* __restrict__ out) {
  const int b = blockIdx.x;
  const int lane = threadIdx.x;
  __shared__ float4 kbox[kDets];
  __shared__ float karea[kDets];
  __shared__ unsigned long long kkey[kDets];
  const unsigned long long* keys = skey + (size_t)b * kNTot;
  const float4* boxes = obox + (size_t)b * kNTot;
  int nkept = 0;
  for (int base = 0; base < kNTot && nkept < kDets; base += 64) {
    int j = base + lane;
    unsigned long long key = (j < kNTot) ? keys[j] : 0ull;
    float sc = __uint_as_float((unsigned int)(key >> 24));
    bool scval = (j < kNTot) && (sc > kScoreT);
    if (__ballot(scval) == 0ull) break;  // sorted desc: nothing valid remains
    float4 bx = make_float4(0.f, 0.f, 0.f, 0.f);
    if (scval) bx = boxes[j];
    float area = (bx.z - bx.x) * (bx.w - bx.y);
    bool alive = scval;
    for (int k = 0; k < nkept; ++k) {
      float4 kb = kbox[k];
      float xx1 = fmaxf(kb.x, bx.x), yy1 = fmaxf(kb.y, bx.y);
      float xx2 = fminf(kb.z, bx.z), yy2 = fminf(kb.w, bx.w);
      float inter = fmaxf(xx2 - xx1, 0.f) * fmaxf(yy2 - yy1, 0.f);
      float iou = inter / (area + karea[k] - inter + 1e-9f);
      if (iou > kNmsT) alive = false;
    }
    unsigned long long mask = __ballot(alive);
    while (mask != 0ull && nkept < kDets) {
      int lead = (int)__builtin_ctzll(mask);
      float lx = __shfl(bx.x, lead);
      float ly = __shfl(bx.y, lead);
      float lz = __shfl(bx.z, lead);
      float lw = __shfl(bx.w, lead);
      float la = __shfl(area, lead);
      unsigned int khi = (unsigned int)__shfl((int)(key >> 32), lead);
      unsigned int klo = (unsigned int)__shfl((int)(key & 0xFFFFFFFFull), lead);
      if (lane == 0) {
        kbox[nkept] = make_float4(lx, ly, lz, lw);
        karea[nkept] = la;
        kkey[nkept] = (((unsigned long long)khi) << 32) | (unsigned long long)klo;
      }
      __syncthreads();
      ++nkept;
      // suppress within chunk vs lead (lead suppresses itself: IoU == 1)
      float xx1 = fmaxf(lx, bx.x), yy1 = fmaxf(ly, bx.y);
      float xx2 = fminf(lz, bx.z), yy2 = fminf(lw, bx.w);
      float inter = fmaxf(xx2 - xx1, 0.f) * fmaxf(yy2 - yy1, 0.f);
      float iou = inter / (area + la - inter + 1e-9f);
      if (iou > kNmsT) alive = false;
      mask = __ballot(alive);
    }
  }
  // outputs: boxes [B,100,4] | scores [B,100] | labels [B,100]
  for (int s = lane; s < kDets; s += 64) {
    float4 bo = make_float4(0.f, 0.f, 0.f, 0.f);
    float so = 0.f, lo = -1.f;
    if (s < nkept) {
      float4 box; int label; float sc;
      decode_key(kkey[s], b, P, &box, &label, &sc);
      bo = box; so = sc; lo = (float)label;
    }
    size_t bi = (size_t)b * kDets + s;
    out[bi * 4 + 0] = bo.x;
    out[bi * 4 + 1] = bo.y;
    out[bi * 4 + 2] = bo.z;
    out[bi * 4 + 3] = bo.w;
    out[(size_t)kB * kDets * 4 + bi] = so;
    out[(size_t)kB * kDets * 5 + bi] = lo;
  }
}

}  // namespace

extern "C" void kernel_launch(void* const* d_in, const int* in_sizes, int n_in,
                              void* d_out, int out_size, void* d_ws, size_t ws_size,
                              hipStream_t stream) {
  ClsPtrs CP; LvlPtrs P;
  const float* ctr[5];
  for (int l = 0; l < 5; ++l) {
    CP.cls[l] = (const float*)d_in[4 * l + 0];
    ctr[l]    = (const float*)d_in[4 * l + 1];
    P.reg[l]  = (const float*)d_in[4 * l + 2];
    P.anc[l]  = (const float*)d_in[4 * l + 3];
  }

  char* w = (char*)d_ws;
  unsigned int* hist = (unsigned int*)w;          w += (size_t)80 * kNBins * 4;  // 655360
  int* cutoff = (int*)w;                          w += 80 * 4;
  unsigned int* cnt = (unsigned int*)w;           w += 80 * 4;
  unsigned long long* cand = (unsigned long long*)w;      w += (size_t)80 * kCap * 8;
  unsigned long long* lvlsorted = (unsigned long long*)w; w += (size_t)80 * kTopK * 8;
  unsigned long long* skeyp = (unsigned long long*)w;     w += (size_t)kB * kNTot * 8;
  float4* oboxp = (float4*)w;                     w += (size_t)kB * kNTot * 16;
  float* sct = (float*)w;                         w += (size_t)kB * kHWTot * 4;

  // zero hist + cutoff + cnt (contiguous)
  hipMemsetAsync(hist, 0, (size_t)80 * kNBins * 4 + 80 * 8, stream);

  int sblocks = (kB * kHWTot + 255) / 256;
  ksigctr<<<sblocks, 256, 0, stream>>>(ctr[0], ctr[1], ctr[2], ctr[3], ctr[4], sct);

  khist_all<<<kB * kChunksPerImg, 256, 0, stream>>>(CP, sct, hist);

  kcutoff<<<80, 256, 0, stream>>>(hist, cutoff);

  kcompact_all<<<kB * kChunksPerImg, 256, 0, stream>>>(CP, sct, cutoff, cnt, cand);

  krankl<<<80, 1024, 0, stream>>>(cand, cnt, lvlsorted);

  int rblocks = (kB * kNTot + 255) / 256;
  krank<<<rblocks, 256, 0, stream>>>(lvlsorted, skeyp, oboxp, P);

  knms<<<kB, 64, 0, stream>>>(skeyp, oboxp, P, (float*)d_out);
}